// Round 8
// baseline (122.902 us; speedup 1.0000x reference)
//
#include <hip/hip_runtime.h>
#include <hip/hip_bf16.h>
#include <cstddef>
#include <cstdint>

// GAT layer: B=8, N=2048, C_IN=128, C_OUT=64, fp32 in/out.
//
// Rank-1 scores: e[b,i,j] = lrelu(s1[b,i] + s2[b,j]); mask = adj>0 | diag.
// Unnormalized softmax (shift-invariant; e bounded => exp fits fp32).
// lrelu(z)=max(z,0.01z) and exp2 monotone => p = max(E1*E2, F1*F2) with
// E=exp2(z·log2e), F=exp2(0.01z·log2e) per row — inner loop has NO exp.
// l row-sum via extra MFMA against all-ones B fragment.
//
// ROUND-8: prep projection was per-CU LDS-pipe bound (512 ds_read_b32/wave =
// ~20 us chip-wide). Fix: W in c-blocked LDS layout Wt2[g][f][4] so each lane
// reads its 4 consecutive c-values as one lane-consecutive ds_read_b128
// (conflict-free), and 8 rows/wave to halve W traffic per row. Mask-pack
// consolidated to 4 adj rows/block.
//
// K1 (gat_prep, 1024 blocks): [0,512) projection (32 rows/block);
//     [512,1024) adj->bitmask (4 rows/block, ballot, diag folded).
// K2 (gat_attn, 512 blocks x 512 thr): 32 i-rows, 2 i-halves x 4 j-quarters;
//     j in 256-chunks; hT chunk DMA'd to LDS (global_load_lds, double-buffered,
//     XOR-swizzled conflict-free ds_read_b128); 16x16x32 bf16 MFMA; l fused.
//
// ws budget (round-1 lesson: stay well under 4 MB): 2M hT + 256K E/F + 512K
// mask = 2.75 MB.

#define B_DIM 8
#define N_DIM 2048
#define C_IN  128
#define C_OUT 64
#define NROWS (B_DIM * N_DIM)   // 16384
#define LOG2E 1.4426950408889634f

typedef short bf16x8 __attribute__((ext_vector_type(8)));
typedef short bf16x4 __attribute__((ext_vector_type(4)));
typedef float f32x4  __attribute__((ext_vector_type(4)));

static __device__ __forceinline__ short f2bf(float x) {
    __hip_bfloat16 b = __float2bfloat16(x);
    return *reinterpret_cast<short*>(&b);
}

// ---------------- Kernel 1: fused projection + mask-pack ----------------
__global__ __launch_bounds__(256) void gat_prep(
    const float* __restrict__ inp,   // [B,N,C_IN]
    const float* __restrict__ W,     // [C_IN,C_OUT]
    const float* __restrict__ a,     // [2*C_OUT]
    const float* __restrict__ adj,   // [N,N]
    __hip_bfloat16* __restrict__ hT, // [B][C_OUT][N] bf16
    float* __restrict__ E1, float* __restrict__ F1,   // [B*N]
    float* __restrict__ E2, float* __restrict__ F2,   // [B*N]
    unsigned long long* __restrict__ mask)  // [N][N/64], diag folded in
{
    __shared__ float Wt2[32 * 256];        // 32 KB: [g][f][cc], byte = g*1024+f*16+cc*4
    __shared__ float a1l[C_OUT], a2l[C_OUT];
    __shared__ float tr[C_OUT][33];        // 32-row transpose buffer (+1 pad)

    const int wave = threadIdx.x >> 6;
    const int lane = threadIdx.x & 63;

    if (blockIdx.x >= 512) {
        // ---- mask-pack block: 4 adj rows ----
        const int ib = (blockIdx.x - 512) * 4;
#pragma unroll
        for (int r = 0; r < 4; ++r) {
            const int i = ib + r;
            const float* __restrict__ arow = adj + (size_t)i * N_DIM;
#pragma unroll
            for (int it = 0; it < 8; ++it) {
                const int j = wave * 512 + it * 64 + lane;
                const bool conn = (arow[j] > 0.f) || (j == i);   // diag folded in
                const unsigned long long bm = __ballot(conn);
                if (lane == 0) mask[(size_t)i * (N_DIM / 64) + (j >> 6)] = bm;
            }
        }
        return;
    }

    // ---- projection block: 32 rows, 8 rows/wave ----
    for (int t = threadIdx.x; t < C_IN * C_OUT; t += 256) {
        const int c = t >> 6, f = t & 63;
        Wt2[((c >> 2) << 8) + (f << 2) + (c & 3)] = W[t];   // c-blocked layout
    }
    if (threadIdx.x < C_OUT) {
        a1l[threadIdx.x] = a[threadIdx.x];
        a2l[threadIdx.x] = a[C_OUT + threadIdx.x];
    }
    __syncthreads();

    const int i0 = blockIdx.x * 32;        // 32 rows/block (never crosses batch)
    const int b  = i0 >> 11;
    const int il = i0 & (N_DIM - 1);
    const int rl = wave * 8;               // this wave's 8 rows

    const float* __restrict__ xp = inp + (size_t)(i0 + rl) * C_IN;
    float hacc[8] = {0.f,0.f,0.f,0.f,0.f,0.f,0.f,0.f};
#pragma unroll 2
    for (int g = 0; g < 32; ++g) {
        const float4 wv = *(const float4*)&Wt2[(g << 8) + (lane << 2)];  // ds_read_b128, conflict-free
#pragma unroll
        for (int r = 0; r < 8; ++r) {
            const float4 xv = *(const float4*)(xp + r * C_IN + g * 4);   // wave-uniform, L1 broadcast
            hacc[r] = fmaf(xv.x, wv.x, hacc[r]);
            hacc[r] = fmaf(xv.y, wv.y, hacc[r]);
            hacc[r] = fmaf(xv.z, wv.z, hacc[r]);
            hacc[r] = fmaf(xv.w, wv.w, hacc[r]);
        }
    }
#pragma unroll
    for (int r = 0; r < 8; ++r) tr[lane][rl + r] = hacc[r];   // (lane+rl+r)%32: 2-way, free

#pragma unroll
    for (int r = 0; r < 8; ++r) {
        float p1 = hacc[r] * a1l[lane];
        float p2 = hacc[r] * a2l[lane];
#pragma unroll
        for (int off = 32; off; off >>= 1) {
            p1 += __shfl_xor(p1, off, 64);
            p2 += __shfl_xor(p2, off, 64);
        }
        if (lane == 0) {
            const float z1 = p1 * LOG2E;   // exp(x) = exp2(x*log2e)
            const float z2 = p2 * LOG2E;
            const int rr = i0 + rl + r;
            E1[rr] = exp2f(z1);
            F1[rr] = exp2f(0.01f * z1);
            E2[rr] = exp2f(z2);
            F2[rr] = exp2f(0.01f * z2);
        }
    }
    __syncthreads();

    // hT[b][f][il+ro4..+4): idx -> f = idx>>3, ro4 = (idx&7)*4
#pragma unroll
    for (int it = 0; it < 2; ++it) {
        const int idx = it * 256 + threadIdx.x;
        const int f   = idx >> 3;
        const int ro4 = (idx & 7) * 4;
        bf16x4 v;
        v[0] = f2bf(tr[f][ro4 + 0]);
        v[1] = f2bf(tr[f][ro4 + 1]);
        v[2] = f2bf(tr[f][ro4 + 2]);
        v[3] = f2bf(tr[f][ro4 + 3]);
        *(bf16x4*)(hT + ((size_t)b * C_OUT + f) * N_DIM + il + ro4) = v;
    }
}

// ---------------- Kernel 2: MFMA attention, double-buffered LDS ----------------
__global__ __launch_bounds__(512, 4) void gat_attn(
    const __hip_bfloat16* __restrict__ hT,        // [B][C_OUT][N]
    const float* __restrict__ E1, const float* __restrict__ F1,
    const float* __restrict__ E2, const float* __restrict__ F2,
    const unsigned long long* __restrict__ mask,  // [N][N/64]
    float* __restrict__ out)                      // [B,N,C_OUT]
{
    __shared__ __align__(16) char smem[2][32768]; // double buffer / epilogue accL
    __shared__ float lred[8][16];

    const int wave = threadIdx.x >> 6;     // 0..7
    const int lane = threadIdx.x & 63;
    const int half = wave >> 2;            // i-half (0/1)
    const int jq   = wave & 3;             // j-quarter within chunk
    const int tb = blockIdx.x;             // 0..511
    const int b  = tb >> 6;                // 64 row-tiles of 32 per batch
    const int i0 = (tb & 63) * 32;
    const int mloc = lane & 15;
    const int quad = lane >> 4;
    const int i_g  = i0 + half * 16 + mloc;

    const float E1v = E1[(size_t)b * N_DIM + i_g];
    const float F1v = F1[(size_t)b * N_DIM + i_g];
    const float* __restrict__ E2b = E2 + (size_t)b * N_DIM;
    const float* __restrict__ F2b = F2 + (size_t)b * N_DIM;
    const uint8_t* __restrict__ mB = (const uint8_t*)mask;   // [N][N/8] bytes (LE)
    const char* __restrict__ hTb = (const char*)(hT + (size_t)b * C_OUT * N_DIM);

    f32x4 acc0 = {0.f,0.f,0.f,0.f}, acc1 = {0.f,0.f,0.f,0.f};
    f32x4 acc2 = {0.f,0.f,0.f,0.f}, acc3 = {0.f,0.f,0.f,0.f};
    f32x4 accl = {0.f,0.f,0.f,0.f};        // l row-sums via ones-MFMA
    const bf16x8 ones = {(short)0x3F80, (short)0x3F80, (short)0x3F80, (short)0x3F80,
                         (short)0x3F80, (short)0x3F80, (short)0x3F80, (short)0x3F80};

    // compute one 256-j chunk from LDS buffer `buf`
    auto compute_chunk = [&](int jc, const char* buf) {
#pragma unroll
        for (int st = 0; st < 2; ++st) {
            const int bjl = jq * 64 + st * 32 + quad * 8;   // within-chunk j
            const int jg  = jc * 256 + bjl;
            const int cA  = bjl >> 3;                       // chunk idx 0..31
            const unsigned mb = mB[(size_t)i_g * (N_DIM / 8) + (jg >> 3)];
            const f32x4 eA = *(const f32x4*)(E2b + jg);
            const f32x4 eB = *(const f32x4*)(E2b + jg + 4);
            const f32x4 fA = *(const f32x4*)(F2b + jg);
            const f32x4 fB = *(const f32x4*)(F2b + jg + 4);
            bf16x8 pf;
#pragma unroll
            for (int t = 0; t < 8; ++t) {
                const float pe = E1v * (t < 4 ? eA[t] : eB[t - 4]);
                const float pn = F1v * (t < 4 ? fA[t] : fB[t - 4]);
                float p = fmaxf(pe, pn);                    // = exp2(lrelu(z))
                p = ((mb >> t) & 1u) ? p : 0.f;
                pf[t] = f2bf(p);
            }
            accl = __builtin_amdgcn_mfma_f32_16x16x32_bf16(pf, ones, accl, 0, 0, 0);
#pragma unroll
            for (int nb = 0; nb < 4; ++nb) {
                const int f  = nb * 16 + mloc;
                const int cS = (cA & 16) | ((cA ^ (f & 15)) & 15);
                const bf16x8 bF = *(const bf16x8*)(buf + (f * 32 + cS) * 16);
                if (nb == 0) acc0 = __builtin_amdgcn_mfma_f32_16x16x32_bf16(pf, bF, acc0, 0, 0, 0);
                if (nb == 1) acc1 = __builtin_amdgcn_mfma_f32_16x16x32_bf16(pf, bF, acc1, 0, 0, 0);
                if (nb == 2) acc2 = __builtin_amdgcn_mfma_f32_16x16x32_bf16(pf, bF, acc2, 0, 0, 0);
                if (nb == 3) acc3 = __builtin_amdgcn_mfma_f32_16x16x32_bf16(pf, bF, acc3, 0, 0, 0);
            }
        }
    };

    for (int jc = 0; jc < 8; ++jc) {
        __syncthreads();   // readers of this buffer (chunk jc-2) done; DMA jc-1 drained
        // DMA chunk jc into smem[jc&1] (swizzled), 4 instr/wave
#pragma unroll
        for (int q = 0; q < 4; ++q) {
            const int p = (wave * 4 + q) * 64 + lane;       // 0..2047
            const int f  = p >> 5;
            const int cs = p & 31;
            const int c  = (cs & 16) | ((cs ^ (f & 15)) & 15);
            const char* gp = hTb + ((size_t)f * N_DIM + jc * 256) * 2 + c * 16;
            char* lp = smem[jc & 1] + (wave * 4 + q) * 1024; // + lane*16 implicit
            __builtin_amdgcn_global_load_lds(
                (const __attribute__((address_space(1))) void*)gp,
                (__attribute__((address_space(3))) void*)lp, 16, 0, 0);
        }
        if (jc > 0) compute_chunk(jc - 1, smem[(jc - 1) & 1]);
    }
    __syncthreads();       // drains DMA of chunk 7
    compute_chunk(7, smem[1]);
    __syncthreads();       // safe to reuse smem[0] as accL

    // l: accl[reg] = row-sum for row quad*4+reg (all cols identical)
    if (mloc == 0) {
#pragma unroll
        for (int reg = 0; reg < 4; ++reg)
            lred[wave][quad * 4 + reg] = accl[reg];
    }

    // C/D layout: row r = quad*4+reg, col f = nb*16+mloc
    float* accL = (float*)smem[0];         // [8][16][64] = 32 KB
#pragma unroll
    for (int reg = 0; reg < 4; ++reg) {
        const int r = quad * 4 + reg;
        accL[(wave * 16 + r) * 64 + 0 * 16 + mloc] = acc0[reg];
        accL[(wave * 16 + r) * 64 + 1 * 16 + mloc] = acc1[reg];
        accL[(wave * 16 + r) * 64 + 2 * 16 + mloc] = acc2[reg];
        accL[(wave * 16 + r) * 64 + 3 * 16 + mloc] = acc3[reg];
    }
    __syncthreads();

    float* __restrict__ ob = out + ((size_t)b * N_DIM + i0) * C_OUT;
#pragma unroll
    for (int e = threadIdx.x; e < 32 * C_OUT; e += 512) {
        const int R = e >> 6;              // output row 0..31
        const int hf = R >> 4;             // which i-half
        const int r  = R & 15;
        float s = 0.f, ls = 0.f;
#pragma unroll
        for (int q = 0; q < 4; ++q) {
            const int w = hf * 4 + q;
            s  += accL[(w * 16 + r) * 64 + (e & 63)];
            ls += lred[w][r];
        }
        ob[e] = s / ls;
    }
}

extern "C" void kernel_launch(void* const* d_in, const int* in_sizes, int n_in,
                              void* d_out, int out_size, void* d_ws, size_t ws_size,
                              hipStream_t stream) {
    const float* inp = (const float*)d_in[0];   // [8,2048,128]
    const float* adj = (const float*)d_in[1];   // [2048,2048]
    const float* W   = (const float*)d_in[2];   // [128,64]
    const float* a   = (const float*)d_in[3];   // [128]
    float* out = (float*)d_out;                 // [8,2048,64]

    // ws layout (2.75 MB total):
    char* ws = (char*)d_ws;
    __hip_bfloat16* hT = (__hip_bfloat16*)ws;                       // 2 MB
    float* E1 = (float*)(ws + (size_t)2 * 1024 * 1024);             // 64 KB
    float* F1 = E1 + NROWS;                                         // 64 KB
    float* E2 = F1 + NROWS;                                         // 64 KB
    float* F2 = E2 + NROWS;                                         // 64 KB
    unsigned long long* mask = (unsigned long long*)(F2 + NROWS);   // 512 KB

    gat_prep<<<1024, 256, 0, stream>>>(inp, W, a, adj, hT, E1, F1, E2, F2, mask);
    gat_attn<<<NROWS / 32, 512, 0, stream>>>(hT, E1, F1, E2, F2, mask, out);
}

// Round 9
// 112.429 us; speedup vs baseline: 1.0931x; 1.0931x over previous
//
#include <hip/hip_runtime.h>
#include <hip/hip_bf16.h>
#include <cstddef>
#include <cstdint>

// GAT layer: B=8, N=2048, C_IN=128, C_OUT=64, fp32 in/out.
//
// Rank-1 scores: e[b,i,j] = lrelu(s1[b,i] + s2[b,j]); mask = adj>0 | diag.
// Unnormalized softmax (shift-invariant; e bounded => exp fits fp32).
// lrelu(z)=max(z,0.01z) and exp2 monotone => p = max(E1*E2, F1*F2) with
// E=exp2(z·log2e), F=exp2(0.01z·log2e) per row — inner loop has NO exp.
// l row-sum via extra MFMA against all-ones B fragment.
//
// ROUND-9: (a) prep reverted to the round-7 version verbatim (round-8's
// restructure regressed +5.9 us). (b) attn restructured: waves = 8 j-eighths,
// each wave computes BOTH 16-row i-subtiles sharing a single B-fragment
// ds_read (r7 had 2 i-half waves reading identical B-frags = 2x redundant
// LDS traffic). ds_read_b128/wave 64 -> 32; E2/F2 loads halved.
//
// K1 (gat_prep, 3072 blocks): [0,1024) projection (h=inp@W, W in LDS, hT bf16
//     [B][C_OUT][N] via LDS transpose, E1/F1/E2/F2); [1024,3072) adj->bitmask.
// K2 (gat_attn, 512 blocks x 512 thr): 32 i-rows; j in 256-chunks; hT chunk
//     DMA'd to LDS (global_load_lds, double-buffered, XOR-swizzled
//     conflict-free ds_read_b128); 16x16x32 bf16 MFMA; l fused via ones-MFMA.
//
// ws budget (round-1 lesson: stay well under 4 MB): 2M hT + 256K E/F + 512K
// mask = 2.75 MB.

#define B_DIM 8
#define N_DIM 2048
#define C_IN  128
#define C_OUT 64
#define NROWS (B_DIM * N_DIM)   // 16384
#define LOG2E 1.4426950408889634f

typedef short bf16x8 __attribute__((ext_vector_type(8)));
typedef short bf16x4 __attribute__((ext_vector_type(4)));
typedef float f32x4  __attribute__((ext_vector_type(4)));

static __device__ __forceinline__ short f2bf(float x) {
    __hip_bfloat16 b = __float2bfloat16(x);
    return *reinterpret_cast<short*>(&b);
}

// ---------------- Kernel 1: fused projection + mask-pack (round-7 version) ----------------
__global__ __launch_bounds__(256) void gat_prep(
    const float* __restrict__ inp,   // [B,N,C_IN]
    const float* __restrict__ W,     // [C_IN,C_OUT]
    const float* __restrict__ a,     // [2*C_OUT]
    const float* __restrict__ adj,   // [N,N]
    __hip_bfloat16* __restrict__ hT, // [B][C_OUT][N] bf16
    float* __restrict__ E1, float* __restrict__ F1,   // [B*N]
    float* __restrict__ E2, float* __restrict__ F2,   // [B*N]
    unsigned long long* __restrict__ mask)  // [N][N/64], diag folded in
{
    __shared__ float Wl[C_IN * C_OUT];     // 32 KB
    __shared__ float a1l[C_OUT], a2l[C_OUT];
    __shared__ float tr[C_OUT][17];        // 16-row transpose buffer, padded

    if (blockIdx.x >= 1024) {
        // ---- mask-pack block: one adj row ----
        const int i    = blockIdx.x - 1024;
        const int wave = threadIdx.x >> 6;
        const int lane = threadIdx.x & 63;
        const float* __restrict__ arow = adj + (size_t)i * N_DIM;
#pragma unroll
        for (int it = 0; it < 8; ++it) {
            const int j = wave * 512 + it * 64 + lane;
            const bool conn = (arow[j] > 0.f) || (j == i);   // diag folded in
            const unsigned long long bm = __ballot(conn);
            if (lane == 0) mask[(size_t)i * (N_DIM / 64) + (j >> 6)] = bm;
        }
        return;
    }

    // ---- projection block: 16 rows ----
    {
        const float4* Wv = (const float4*)W;
        float4* Wd = (float4*)Wl;
        for (int t = threadIdx.x; t < C_IN * C_OUT / 4; t += 256) Wd[t] = Wv[t];
        if (threadIdx.x < C_OUT) {
            a1l[threadIdx.x] = a[threadIdx.x];
            a2l[threadIdx.x] = a[C_OUT + threadIdx.x];
        }
    }
    __syncthreads();

    const int wave = threadIdx.x >> 6;
    const int lane = threadIdx.x & 63;
    const int i0 = blockIdx.x * 16;        // 16 rows per block (never crosses batch)
    const int b  = i0 >> 11;
    const int il = i0 & (N_DIM - 1);
    const int rl = wave * 4;               // this wave's 4 rows

    const float* __restrict__ x0 = inp + (size_t)(i0 + rl) * C_IN;
    const float* __restrict__ x1 = x0 + C_IN;
    const float* __restrict__ x2 = x1 + C_IN;
    const float* __restrict__ x3 = x2 + C_IN;
    float h0 = 0.f, h1 = 0.f, h2 = 0.f, h3 = 0.f;
#pragma unroll 4
    for (int c = 0; c < C_IN; c += 4) {
        const float4 a0 = *(const float4*)(x0 + c);
        const float4 a1 = *(const float4*)(x1 + c);
        const float4 a2 = *(const float4*)(x2 + c);
        const float4 a3 = *(const float4*)(x3 + c);
#pragma unroll
        for (int cc = 0; cc < 4; ++cc) {
            const float w_ = Wl[(c + cc) * C_OUT + lane];
            const float e0 = (cc==0)?a0.x:(cc==1)?a0.y:(cc==2)?a0.z:a0.w;
            const float e1 = (cc==0)?a1.x:(cc==1)?a1.y:(cc==2)?a1.z:a1.w;
            const float e2 = (cc==0)?a2.x:(cc==1)?a2.y:(cc==2)?a2.z:a2.w;
            const float e3 = (cc==0)?a3.x:(cc==1)?a3.y:(cc==2)?a3.z:a3.w;
            h0 = fmaf(e0, w_, h0);
            h1 = fmaf(e1, w_, h1);
            h2 = fmaf(e2, w_, h2);
            h3 = fmaf(e3, w_, h3);
        }
    }
    tr[lane][rl + 0] = h0;                 // stride 17: conflict-free
    tr[lane][rl + 1] = h1;
    tr[lane][rl + 2] = h2;
    tr[lane][rl + 3] = h3;

    float hv[4] = {h0, h1, h2, h3};
#pragma unroll
    for (int k = 0; k < 4; ++k) {
        float p1 = hv[k] * a1l[lane];
        float p2 = hv[k] * a2l[lane];
#pragma unroll
        for (int off = 32; off; off >>= 1) {
            p1 += __shfl_xor(p1, off, 64);
            p2 += __shfl_xor(p2, off, 64);
        }
        if (lane == 0) {
            const float z1 = p1 * LOG2E;   // exp(x) = exp2(x*log2e)
            const float z2 = p2 * LOG2E;
            const int r = i0 + rl + k;
            E1[r] = exp2f(z1);
            F1[r] = exp2f(0.01f * z1);
            E2[r] = exp2f(z2);
            F2[r] = exp2f(0.01f * z2);
        }
    }
    __syncthreads();

    // hT[b][f][il+ro4..+4): thread t -> f = t>>2, ro4 = (t&3)*4
    const int f   = threadIdx.x >> 2;
    const int ro4 = (threadIdx.x & 3) * 4;
    bf16x4 v;
    v[0] = f2bf(tr[f][ro4 + 0]);
    v[1] = f2bf(tr[f][ro4 + 1]);
    v[2] = f2bf(tr[f][ro4 + 2]);
    v[3] = f2bf(tr[f][ro4 + 3]);
    *(bf16x4*)(hT + ((size_t)b * C_OUT + f) * N_DIM + il + ro4) = v;
}

// ---------------- Kernel 2: MFMA attention, dbuf LDS, shared B-frags ----------------
// 8 waves = 8 j-eighths (32 j each per 256-chunk); each wave computes BOTH
// 16-row i-subtiles, sharing one B-fragment ds_read per (nb).
__global__ __launch_bounds__(512, 4) void gat_attn(
    const __hip_bfloat16* __restrict__ hT,        // [B][C_OUT][N]
    const float* __restrict__ E1, const float* __restrict__ F1,
    const float* __restrict__ E2, const float* __restrict__ F2,
    const unsigned long long* __restrict__ mask,  // [N][N/64]
    float* __restrict__ out)                      // [B,N,C_OUT]
{
    __shared__ __align__(16) char smem[2][32768]; // double buffer / epilogue accL (64 KB)
    __shared__ float lred[8][2][16];

    const int wave = threadIdx.x >> 6;     // 0..7 = j-eighth
    const int lane = threadIdx.x & 63;
    const int tb = blockIdx.x;             // 0..511
    const int b  = tb >> 6;                // 64 row-tiles of 32 per batch
    const int i0 = (tb & 63) * 32;
    const int mloc = lane & 15;
    const int quad = lane >> 4;
    const int igA  = i0 + mloc;            // subtile A row (local to batch)
    const int igB  = i0 + 16 + mloc;       // subtile B row

    const float E1A = E1[(size_t)b * N_DIM + igA];
    const float F1A = F1[(size_t)b * N_DIM + igA];
    const float E1B = E1[(size_t)b * N_DIM + igB];
    const float F1B = F1[(size_t)b * N_DIM + igB];
    const float* __restrict__ E2b = E2 + (size_t)b * N_DIM;
    const float* __restrict__ F2b = F2 + (size_t)b * N_DIM;
    const uint8_t* __restrict__ mA = (const uint8_t*)mask + (size_t)igA * (N_DIM / 8);
    const uint8_t* __restrict__ mBp = (const uint8_t*)mask + (size_t)igB * (N_DIM / 8);
    const char* __restrict__ hTb = (const char*)(hT + (size_t)b * C_OUT * N_DIM);

    f32x4 aA0 = {0,0,0,0}, aA1 = {0,0,0,0}, aA2 = {0,0,0,0}, aA3 = {0,0,0,0};
    f32x4 aB0 = {0,0,0,0}, aB1 = {0,0,0,0}, aB2 = {0,0,0,0}, aB3 = {0,0,0,0};
    f32x4 lA = {0,0,0,0}, lB = {0,0,0,0};  // l row-sums via ones-MFMA
    const bf16x8 ones = {(short)0x3F80, (short)0x3F80, (short)0x3F80, (short)0x3F80,
                         (short)0x3F80, (short)0x3F80, (short)0x3F80, (short)0x3F80};

    const int bjl = wave * 32 + quad * 8;  // this lane's within-chunk j base
    const int cA  = bjl >> 3;              // 16B-chunk idx 0..31

    // compute one 256-j chunk from LDS buffer `buf`
    auto compute_chunk = [&](int jc, const char* buf) {
        const int jg = jc * 256 + bjl;
        const unsigned mbA = mA[jg >> 3];
        const unsigned mbB = mBp[jg >> 3];
        const f32x4 eA = *(const f32x4*)(E2b + jg);
        const f32x4 eB = *(const f32x4*)(E2b + jg + 4);
        const f32x4 fA = *(const f32x4*)(F2b + jg);
        const f32x4 fB = *(const f32x4*)(F2b + jg + 4);
        bf16x8 pf0, pf1;
#pragma unroll
        for (int t = 0; t < 8; ++t) {
            const float ev = (t < 4 ? eA[t] : eB[t - 4]);
            const float fv = (t < 4 ? fA[t] : fB[t - 4]);
            float p0 = fmaxf(E1A * ev, F1A * fv);      // = exp2(lrelu(zA))
            p0 = ((mbA >> t) & 1u) ? p0 : 0.f;
            pf0[t] = f2bf(p0);
            float p1 = fmaxf(E1B * ev, F1B * fv);
            p1 = ((mbB >> t) & 1u) ? p1 : 0.f;
            pf1[t] = f2bf(p1);
        }
        lA = __builtin_amdgcn_mfma_f32_16x16x32_bf16(pf0, ones, lA, 0, 0, 0);
        lB = __builtin_amdgcn_mfma_f32_16x16x32_bf16(pf1, ones, lB, 0, 0, 0);
#pragma unroll
        for (int nb = 0; nb < 4; ++nb) {
            const int f  = nb * 16 + mloc;
            const int cS = (cA & 16) | ((cA ^ (f & 15)) & 15);
            const bf16x8 bF = *(const bf16x8*)(buf + (f * 32 + cS) * 16);  // shared by both subtiles
            if (nb == 0) { aA0 = __builtin_amdgcn_mfma_f32_16x16x32_bf16(pf0, bF, aA0, 0, 0, 0);
                           aB0 = __builtin_amdgcn_mfma_f32_16x16x32_bf16(pf1, bF, aB0, 0, 0, 0); }
            if (nb == 1) { aA1 = __builtin_amdgcn_mfma_f32_16x16x32_bf16(pf0, bF, aA1, 0, 0, 0);
                           aB1 = __builtin_amdgcn_mfma_f32_16x16x32_bf16(pf1, bF, aB1, 0, 0, 0); }
            if (nb == 2) { aA2 = __builtin_amdgcn_mfma_f32_16x16x32_bf16(pf0, bF, aA2, 0, 0, 0);
                           aB2 = __builtin_amdgcn_mfma_f32_16x16x32_bf16(pf1, bF, aB2, 0, 0, 0); }
            if (nb == 3) { aA3 = __builtin_amdgcn_mfma_f32_16x16x32_bf16(pf0, bF, aA3, 0, 0, 0);
                           aB3 = __builtin_amdgcn_mfma_f32_16x16x32_bf16(pf1, bF, aB3, 0, 0, 0); }
        }
    };

    for (int jc = 0; jc < 8; ++jc) {
        __syncthreads();   // readers of this buffer (chunk jc-2) done; DMA jc-1 drained
        // DMA chunk jc into smem[jc&1] (swizzled), 4 instr/wave
#pragma unroll
        for (int q = 0; q < 4; ++q) {
            const int p = (wave * 4 + q) * 64 + lane;       // 0..2047
            const int f  = p >> 5;
            const int cs = p & 31;
            const int c  = (cs & 16) | ((cs ^ (f & 15)) & 15);
            const char* gp = hTb + ((size_t)f * N_DIM + jc * 256) * 2 + c * 16;
            char* lp = smem[jc & 1] + (wave * 4 + q) * 1024; // + lane*16 implicit
            __builtin_amdgcn_global_load_lds(
                (const __attribute__((address_space(1))) void*)gp,
                (__attribute__((address_space(3))) void*)lp, 16, 0, 0);
        }
        if (jc > 0) compute_chunk(jc - 1, smem[(jc - 1) & 1]);
    }
    __syncthreads();       // drains DMA of chunk 7
    compute_chunk(7, smem[1]);
    __syncthreads();       // safe to reuse smem as accL

    // l: lX[reg] = row-sum for row quad*4+reg (all 16 cols identical)
    if (mloc == 0) {
#pragma unroll
        for (int reg = 0; reg < 4; ++reg) {
            lred[wave][0][quad * 4 + reg] = lA[reg];
            lred[wave][1][quad * 4 + reg] = lB[reg];
        }
    }

    // C/D layout: row r = quad*4+reg, col f = nb*16+mloc
    float* accL = (float*)smem;            // [8 waves][2 halves][16 rows][64 f] = 64 KB
#pragma unroll
    for (int reg = 0; reg < 4; ++reg) {
        const int r = quad * 4 + reg;
        float* pa = accL + ((wave * 2 + 0) * 16 + r) * 64 + mloc;
        float* pb = accL + ((wave * 2 + 1) * 16 + r) * 64 + mloc;
        pa[ 0] = aA0[reg]; pa[16] = aA1[reg]; pa[32] = aA2[reg]; pa[48] = aA3[reg];
        pb[ 0] = aB0[reg]; pb[16] = aB1[reg]; pb[32] = aB2[reg]; pb[48] = aB3[reg];
    }
    __syncthreads();

    float* __restrict__ ob = out + ((size_t)b * N_DIM + i0) * C_OUT;
#pragma unroll
    for (int e = threadIdx.x; e < 32 * C_OUT; e += 512) {
        const int R  = e >> 6;             // output row 0..31
        const int hf = R >> 4;             // which i-subtile
        const int r  = R & 15;
        const int fc = e & 63;
        float s = 0.f, ls = 0.f;
#pragma unroll
        for (int w = 0; w < 8; ++w) {
            s  += accL[((w * 2 + hf) * 16 + r) * 64 + fc];
            ls += lred[w][hf][r];
        }
        ob[e] = s / ls;
    }
}

extern "C" void kernel_launch(void* const* d_in, const int* in_sizes, int n_in,
                              void* d_out, int out_size, void* d_ws, size_t ws_size,
                              hipStream_t stream) {
    const float* inp = (const float*)d_in[0];   // [8,2048,128]
    const float* adj = (const float*)d_in[1];   // [2048,2048]
    const float* W   = (const float*)d_in[2];   // [128,64]
    const float* a   = (const float*)d_in[3];   // [128]
    float* out = (float*)d_out;                 // [8,2048,64]

    // ws layout (2.75 MB total):
    char* ws = (char*)d_ws;
    __hip_bfloat16* hT = (__hip_bfloat16*)ws;                       // 2 MB
    float* E1 = (float*)(ws + (size_t)2 * 1024 * 1024);             // 64 KB
    float* F1 = E1 + NROWS;                                         // 64 KB
    float* E2 = F1 + NROWS;                                         // 64 KB
    float* F2 = E2 + NROWS;                                         // 64 KB
    unsigned long long* mask = (unsigned long long*)(F2 + NROWS);   // 512 KB

    gat_prep<<<1024 + N_DIM, 256, 0, stream>>>(inp, W, a, adj, hT, E1, F1, E2, F2, mask);
    gat_attn<<<NROWS / 32, 512, 0, stream>>>(hT, E1, F1, E2, F2, mask, out);
}